// Round 2
// baseline (921.556 us; speedup 1.0000x reference)
//
#include <hip/hip_runtime.h>
#include <hip/hip_bf16.h>
#include <math.h>

typedef __bf16 bf16;
typedef __bf16 bf16x8 __attribute__((ext_vector_type(8)));
typedef float f32x4 __attribute__((ext_vector_type(4)));

#define AS1(p) ((const __attribute__((address_space(1))) void*)(p))
#define AS3(p) ((__attribute__((address_space(3))) void*)(p))

__device__ __forceinline__ void gl_lds16(const bf16* g, bf16* l) {
    __builtin_amdgcn_global_load_lds(AS1(g), AS3(l), 16, 0, 0);
}

// ---------------- cast f32 -> bf16, vectorized ----------------
__global__ __launch_bounds__(256) void cast_f32_bf16(const float* __restrict__ in,
                                                     bf16* __restrict__ out, long n) {
    long i = ((long)blockIdx.x * 256 + threadIdx.x) * 4;
    if (i + 3 < n) {
        float4 v = *(const float4*)(in + i);
        out[i + 0] = (bf16)v.x;
        out[i + 1] = (bf16)v.y;
        out[i + 2] = (bf16)v.z;
        out[i + 3] = (bf16)v.w;
    }
}

// ---------------- transpose + cast: in[R][C] f32 -> out[C][R] bf16 ----------------
__global__ __launch_bounds__(256) void transpose_cast(const float* __restrict__ in,
                                                      bf16* __restrict__ out,
                                                      int R, int Cc) {
    __shared__ float tile[32][33];
    const int t = threadIdx.x;
    const int r0 = blockIdx.y * 32, c0 = blockIdx.x * 32;
    for (int i = 0; i < 4; ++i) {
        int idx = t + i * 256;
        int r = idx >> 5, c = idx & 31;
        tile[r][c] = in[(size_t)(r0 + r) * Cc + c0 + c];
    }
    __syncthreads();
    for (int i = 0; i < 4; ++i) {
        int idx = t + i * 256;
        int r = idx >> 5, c = idx & 31;
        out[(size_t)(c0 + r) * R + r0 + c] = (bf16)tile[c][r];
    }
}

// ---------------- GEMM: C[M][N] = A[M][K] * B, with BT[N][K] given (bf16 in) ---------
// 128x128 tile, BK=32, 4 waves, each wave 64x64 (4x4 frags of 16x16x32 bf16 MFMA).
template <typename OT>
__global__ __launch_bounds__(256) void gemm_bt(const bf16* __restrict__ A,
                                               const bf16* __restrict__ BT,
                                               OT* __restrict__ C,
                                               int M, int N, int K) {
    __shared__ bf16 lA[128 * 32];
    __shared__ bf16 lB[128 * 32];
    const int t = threadIdx.x;
    const int lane = t & 63;
    const int w = t >> 6;
    const int wr = w >> 1, wc = w & 1;
    const int l15 = lane & 15, lg = lane >> 4;
    const int bm = blockIdx.y, bn = blockIdx.x;

    const bf16* Abase = A + (size_t)bm * 128 * K;
    const bf16* Bbase = BT + (size_t)bn * 128 * K;

    f32x4 acc[4][4] = {};

    for (int k0 = 0; k0 < K; k0 += 32) {
        for (int j = 0; j < 2; ++j) {
            int c = j * 256 + t;                 // chunk id 0..511
            int r = c >> 2, col = (c & 3) * 8;   // tile row, elem col
            gl_lds16(Abase + (size_t)r * K + k0 + col, lA + (size_t)(j * 256 + w * 64) * 8);
            gl_lds16(Bbase + (size_t)r * K + k0 + col, lB + (size_t)(j * 256 + w * 64) * 8);
        }
        __syncthreads();
        bf16x8 af[4], bfr[4];
        for (int m = 0; m < 4; ++m)
            af[m] = *(const bf16x8*)(lA + (wr * 64 + m * 16 + l15) * 32 + lg * 8);
        for (int n = 0; n < 4; ++n)
            bfr[n] = *(const bf16x8*)(lB + (wc * 64 + n * 16 + l15) * 32 + lg * 8);
        for (int m = 0; m < 4; ++m)
            for (int n = 0; n < 4; ++n)
                acc[m][n] = __builtin_amdgcn_mfma_f32_16x16x32_bf16(af[m], bfr[n], acc[m][n], 0, 0, 0);
        __syncthreads();
    }

    for (int m = 0; m < 4; ++m)
        for (int n = 0; n < 4; ++n) {
            int row = bm * 128 + wr * 64 + m * 16 + lg * 4;
            int col = bn * 128 + wc * 64 + n * 16 + l15;
            for (int r = 0; r < 4; ++r)
                C[(size_t)(row + r) * N + col] = (OT)acc[m][n][r];
        }
}

// ---------------- causal flash attention ----------------
// QKV[8192][6144] bf16 (q|k|v each 2048 cols; head h at cols h*128..h*128+127).
// grid: (T/64, B*H). Block: 256 thr = 4 waves, each wave owns 16 q-rows.
__global__ __launch_bounds__(256) void attn_fwd(const bf16* __restrict__ QKV,
                                                bf16* __restrict__ O) {
    __shared__ bf16 lK[32 * 128];    // K-tile [32 kv][128 hd], linear
    __shared__ bf16 lVt[128 * 32];   // V-tile transposed [128 hd][32 kv]
    __shared__ bf16 lP[4][16 * 32];  // per-wave P scratch

    const int t = threadIdx.x, lane = t & 63, w = t >> 6;
    const int l15 = lane & 15, lg = lane >> 4;
    const int bh = blockIdx.y;
    const int b = bh >> 4, h = bh & 15;
    const int q0 = blockIdx.x * 64;
    const int qw = q0 + w * 16;
    const size_t rs = 6144;

    const bf16* Qb = QKV + (size_t)b * 2048 * rs + h * 128;
    const bf16* Kb = Qb + 2048;
    const bf16* Vb = Qb + 4096;

    bf16x8 qf[4];
    for (int kk = 0; kk < 4; ++kk)
        qf[kk] = *(const bf16x8*)(Qb + (size_t)(qw + l15) * rs + kk * 32 + lg * 8);

    f32x4 o[8] = {};
    float mrow[4] = {-1e30f, -1e30f, -1e30f, -1e30f};
    float lrow[4] = {0.f, 0.f, 0.f, 0.f};
    const float scale = 0.08838834764831845f;  // 128^-0.5

    const int ntiles = q0 / 32 + 2;
    for (int kt = 0; kt < ntiles; ++kt) {
        const int kv0 = kt * 32;
        for (int j = 0; j < 2; ++j) {
            int c = j * 256 + t;
            int r = c >> 4, col = (c & 15) * 8;
            gl_lds16(Kb + (size_t)(kv0 + r) * rs + col, lK + (size_t)(j * 256 + w * 64) * 8);
        }
        {
            int kv = t & 31, hgrp = t >> 5;
            for (int u = 0; u < 2; ++u) {
                int hd0 = hgrp * 16 + u * 8;
                bf16x8 v = *(const bf16x8*)(Vb + (size_t)(kv0 + kv) * rs + hd0);
                for (int e = 0; e < 8; ++e)
                    lVt[(hd0 + e) * 32 + kv] = v[e];
            }
        }
        __syncthreads();

        f32x4 s[2] = {};
        for (int n = 0; n < 2; ++n)
            for (int kk = 0; kk < 4; ++kk) {
                bf16x8 kf = *(const bf16x8*)(lK + (n * 16 + l15) * 128 + kk * 32 + lg * 8);
                s[n] = __builtin_amdgcn_mfma_f32_16x16x32_bf16(qf[kk], kf, s[n], 0, 0, 0);
            }

        float pv[2][4];
        for (int n = 0; n < 2; ++n)
            for (int r = 0; r < 4; ++r) {
                float x = s[n][r] * scale;
                int qg = qw + lg * 4 + r;
                int kg = kv0 + n * 16 + l15;
                pv[n][r] = (kg <= qg) ? x : -1e30f;
            }
        float tmax[4];
        for (int r = 0; r < 4; ++r) tmax[r] = fmaxf(pv[0][r], pv[1][r]);
        for (int d = 1; d < 16; d <<= 1)
            for (int r = 0; r < 4; ++r)
                tmax[r] = fmaxf(tmax[r], __shfl_xor(tmax[r], d));
        float alpha[4];
        for (int r = 0; r < 4; ++r) {
            float mn = fmaxf(mrow[r], tmax[r]);
            alpha[r] = __expf(mrow[r] - mn);
            mrow[r] = mn;
        }
        for (int j = 0; j < 8; ++j)
            for (int r = 0; r < 4; ++r) o[j][r] *= alpha[r];
        for (int r = 0; r < 4; ++r) lrow[r] *= alpha[r];
        for (int n = 0; n < 2; ++n)
            for (int r = 0; r < 4; ++r) {
                float p = __expf(pv[n][r] - mrow[r]);
                lrow[r] += p;
                lP[w][(lg * 4 + r) * 32 + n * 16 + l15] = (bf16)p;
            }
        bf16x8 pf = *(const bf16x8*)(&lP[w][l15 * 32 + lg * 8]);
        for (int j = 0; j < 8; ++j) {
            bf16x8 vf = *(const bf16x8*)(lVt + (j * 16 + l15) * 32 + lg * 8);
            o[j] = __builtin_amdgcn_mfma_f32_16x16x32_bf16(pf, vf, o[j], 0, 0, 0);
        }
        __syncthreads();
    }

    for (int d = 1; d < 16; d <<= 1)
        for (int r = 0; r < 4; ++r) lrow[r] += __shfl_xor(lrow[r], d);
    float inv[4];
    for (int r = 0; r < 4; ++r) inv[r] = 1.f / lrow[r];
    bf16* Ob = O + ((size_t)b * 2048 + qw) * 2048 + h * 128;
    for (int j = 0; j < 8; ++j)
        for (int r = 0; r < 4; ++r)
            Ob[(size_t)(lg * 4 + r) * 2048 + j * 16 + l15] = (bf16)(o[j][r] * inv[r]);
}

extern "C" void kernel_launch(void* const* d_in, const int* in_sizes, int n_in,
                              void* d_out, int out_size, void* d_ws, size_t ws_size,
                              hipStream_t stream) {
    const float* x     = (const float*)d_in[0];   // [8192][2048] f32
    const float* wqkv  = (const float*)d_in[1];   // [2048][6144] f32
    const float* wproj = (const float*)d_in[2];   // [2048][2048] f32
    float* out = (float*)d_out;                   // [8192][2048] f32

    char* ws = (char*)d_ws;
    bf16* xb     = (bf16*)(ws);                                   // 8192*2048*2 = 33554432
    bf16* wqkvT  = (bf16*)(ws + 33554432);                        // 6144*2048*2 = 25165824
    bf16* wprojT = (bf16*)(ws + 33554432 + 25165824);             // 2048*2048*2 =  8388608
    bf16* QKV    = (bf16*)(ws + 33554432 + 25165824 + 8388608);   // 8192*6144*2 = 100663296
    bf16* Obuf   = xb;  // aliases xb — x dead after GEMM1

    cast_f32_bf16<<<dim3(16384), 256, 0, stream>>>(x, xb, (long)8192 * 2048);
    transpose_cast<<<dim3(192, 64), 256, 0, stream>>>(wqkv, wqkvT, 2048, 6144);
    transpose_cast<<<dim3(64, 64), 256, 0, stream>>>(wproj, wprojT, 2048, 2048);
    gemm_bt<bf16><<<dim3(48, 64), 256, 0, stream>>>(xb, wqkvT, QKV, 8192, 6144, 2048);
    attn_fwd<<<dim3(32, 64), 256, 0, stream>>>(QKV, Obuf);
    gemm_bt<float><<<dim3(16, 64), 256, 0, stream>>>(Obuf, wprojT, out, 8192, 2048, 2048);
}

// Round 3
// 759.436 us; speedup vs baseline: 1.2135x; 1.2135x over previous
//
#include <hip/hip_runtime.h>
#include <hip/hip_bf16.h>
#include <math.h>

typedef __bf16 bf16;
typedef __bf16 bf16x8 __attribute__((ext_vector_type(8)));
typedef float f32x4 __attribute__((ext_vector_type(4)));

#define AS1(p) ((const __attribute__((address_space(1))) void*)(p))
#define AS3(p) ((__attribute__((address_space(3))) void*)(p))

__device__ __forceinline__ void gl_lds16(const bf16* g, bf16* l) {
    __builtin_amdgcn_global_load_lds(AS1(g), AS3(l), 16, 0, 0);
}

// ---------------- cast f32 -> bf16, vectorized ----------------
__global__ __launch_bounds__(256) void cast_f32_bf16(const float* __restrict__ in,
                                                     bf16* __restrict__ out, long n) {
    long i = ((long)blockIdx.x * 256 + threadIdx.x) * 4;
    if (i + 3 < n) {
        float4 v = *(const float4*)(in + i);
        out[i + 0] = (bf16)v.x;
        out[i + 1] = (bf16)v.y;
        out[i + 2] = (bf16)v.z;
        out[i + 3] = (bf16)v.w;
    }
}

// ---------------- transpose + cast: in[R][C] f32 -> out[C][R] bf16 ----------------
__global__ __launch_bounds__(256) void transpose_cast(const float* __restrict__ in,
                                                      bf16* __restrict__ out,
                                                      int R, int Cc) {
    __shared__ float tile[32][33];
    const int t = threadIdx.x;
    const int r0 = blockIdx.y * 32, c0 = blockIdx.x * 32;
    for (int i = 0; i < 4; ++i) {
        int idx = t + i * 256;
        int r = idx >> 5, c = idx & 31;
        tile[r][c] = in[(size_t)(r0 + r) * Cc + c0 + c];
    }
    __syncthreads();
    for (int i = 0; i < 4; ++i) {
        int idx = t + i * 256;
        int r = idx >> 5, c = idx & 31;
        out[(size_t)(c0 + r) * R + r0 + c] = (bf16)tile[c][r];
    }
}

// ---------------- GEMM: C[M][N] = A[M][K] * B, with BT[N][K] given (bf16 in) ---------
template <typename OT>
__global__ __launch_bounds__(256) void gemm_bt(const bf16* __restrict__ A,
                                               const bf16* __restrict__ BT,
                                               OT* __restrict__ C,
                                               int M, int N, int K) {
    __shared__ bf16 lA[128 * 32];
    __shared__ bf16 lB[128 * 32];
    const int t = threadIdx.x;
    const int lane = t & 63;
    const int w = t >> 6;
    const int wr = w >> 1, wc = w & 1;
    const int l15 = lane & 15, lg = lane >> 4;
    const int bm = blockIdx.y, bn = blockIdx.x;

    const bf16* Abase = A + (size_t)bm * 128 * K;
    const bf16* Bbase = BT + (size_t)bn * 128 * K;

    f32x4 acc[4][4] = {};

    for (int k0 = 0; k0 < K; k0 += 32) {
        for (int j = 0; j < 2; ++j) {
            int c = j * 256 + t;                 // chunk id 0..511
            int r = c >> 2, col = (c & 3) * 8;   // tile row, elem col
            gl_lds16(Abase + (size_t)r * K + k0 + col, lA + (size_t)(j * 256 + w * 64) * 8);
            gl_lds16(Bbase + (size_t)r * K + k0 + col, lB + (size_t)(j * 256 + w * 64) * 8);
        }
        __syncthreads();
        bf16x8 af[4], bfr[4];
        for (int m = 0; m < 4; ++m)
            af[m] = *(const bf16x8*)(lA + (wr * 64 + m * 16 + l15) * 32 + lg * 8);
        for (int n = 0; n < 4; ++n)
            bfr[n] = *(const bf16x8*)(lB + (wc * 64 + n * 16 + l15) * 32 + lg * 8);
        for (int m = 0; m < 4; ++m)
            for (int n = 0; n < 4; ++n)
                acc[m][n] = __builtin_amdgcn_mfma_f32_16x16x32_bf16(af[m], bfr[n], acc[m][n], 0, 0, 0);
        __syncthreads();
    }

    for (int m = 0; m < 4; ++m)
        for (int n = 0; n < 4; ++n) {
            int row = bm * 128 + wr * 64 + m * 16 + lg * 4;
            int col = bn * 128 + wc * 64 + n * 16 + l15;
            for (int r = 0; r < 4; ++r)
                C[(size_t)(row + r) * N + col] = (OT)acc[m][n][r];
        }
}

// ---------------- causal flash attention ----------------
// QKV[8192][6144] bf16. grid: (T/64, B*H), 4 waves, each wave 16 q-rows.
// lK XOR-swizzled (both-sides with global_load_lds); lVt/lP padded to 40.
__global__ __launch_bounds__(256) void attn_fwd(const bf16* __restrict__ QKV,
                                                bf16* __restrict__ O) {
    __shared__ bf16 lK[32 * 128];    // [32 kv][16 chunks of 8], chunk col XOR (row&7)
    __shared__ bf16 lVt[128 * 40];   // V^T [128 hd][32 kv + 8 pad]
    __shared__ bf16 lP[4][16 * 40];  // per-wave P [16 q][32 kv + 8 pad]

    const int t = threadIdx.x, lane = t & 63, w = t >> 6;
    const int l15 = lane & 15, lg = lane >> 4;
    const int bh = blockIdx.y;
    const int b = bh >> 4, h = bh & 15;
    const int q0 = ((int)gridDim.x - 1 - (int)blockIdx.x) * 64;  // largest work first
    const int qw = q0 + w * 16;
    const size_t rs = 6144;

    const bf16* Qb = QKV + (size_t)b * 2048 * rs + h * 128;
    const bf16* Kb = Qb + 2048;
    const bf16* Vb = Qb + 4096;

    bf16x8 qf[4];
    for (int kk = 0; kk < 4; ++kk)
        qf[kk] = *(const bf16x8*)(Qb + (size_t)(qw + l15) * rs + kk * 32 + lg * 8);

    f32x4 o[8] = {};
    float mrow[4] = {-1e30f, -1e30f, -1e30f, -1e30f};
    float lrow[4] = {0.f, 0.f, 0.f, 0.f};
    const float scale = 0.08838834764831845f;  // 128^-0.5

    const int ntiles = q0 / 32 + 2;
    for (int kt = 0; kt < ntiles; ++kt) {
        const int kv0 = kt * 32;
        // stage K tile (32x128) swizzled: LDS chunk c holds global chunk (c&15)^(r&7)
        for (int j = 0; j < 2; ++j) {
            int c = j * 256 + t;
            int r = c >> 4;
            int srcc = (c & 15) ^ (r & 7);
            gl_lds16(Kb + (size_t)(kv0 + r) * rs + srcc * 8, lK + (size_t)(j * 256 + w * 64) * 8);
        }
        // stage V transposed, packed u32 pair-writes, padded rows (40)
        {
            int kvp = t & 15, hd0 = (t >> 4) * 8;
            bf16x8 v0 = *(const bf16x8*)(Vb + (size_t)(kv0 + 2 * kvp) * rs + hd0);
            bf16x8 v1 = *(const bf16x8*)(Vb + (size_t)(kv0 + 2 * kvp + 1) * rs + hd0);
            for (int e = 0; e < 8; ++e) {
                union { bf16 b[2]; unsigned u; } p;
                p.b[0] = v0[e]; p.b[1] = v1[e];
                *(unsigned*)(lVt + (hd0 + e) * 40 + 2 * kvp) = p.u;
            }
        }
        __syncthreads();

        // S = Q K^T (16 q x 32 kv); swizzled K read
        f32x4 s[2] = {};
        for (int n = 0; n < 2; ++n) {
            int row = n * 16 + l15;
            for (int kk = 0; kk < 4; ++kk) {
                int chunk = (kk * 4 + lg) ^ (row & 7);
                bf16x8 kf = *(const bf16x8*)(lK + row * 128 + chunk * 8);
                s[n] = __builtin_amdgcn_mfma_f32_16x16x32_bf16(qf[kk], kf, s[n], 0, 0, 0);
            }
        }

        float pv[2][4];
        for (int n = 0; n < 2; ++n)
            for (int r = 0; r < 4; ++r) {
                float x = s[n][r] * scale;
                int qg = qw + lg * 4 + r;
                int kg = kv0 + n * 16 + l15;
                pv[n][r] = (kg <= qg) ? x : -1e30f;
            }
        float tmax[4];
        for (int r = 0; r < 4; ++r) tmax[r] = fmaxf(pv[0][r], pv[1][r]);
        for (int d = 1; d < 16; d <<= 1)
            for (int r = 0; r < 4; ++r)
                tmax[r] = fmaxf(tmax[r], __shfl_xor(tmax[r], d));
        float alpha[4];
        for (int r = 0; r < 4; ++r) {
            float mn = fmaxf(mrow[r], tmax[r]);
            alpha[r] = __expf(mrow[r] - mn);
            mrow[r] = mn;
        }
        for (int j = 0; j < 8; ++j)
            for (int r = 0; r < 4; ++r) o[j][r] *= alpha[r];
        for (int r = 0; r < 4; ++r) lrow[r] *= alpha[r];
        for (int n = 0; n < 2; ++n)
            for (int r = 0; r < 4; ++r) {
                float p = __expf(pv[n][r] - mrow[r]);
                lrow[r] += p;
                lP[w][(lg * 4 + r) * 40 + n * 16 + l15] = (bf16)p;
            }
        bf16x8 pf = *(const bf16x8*)(&lP[w][l15 * 40 + lg * 8]);
        // O += P V  (V^T rows at stride 40)
        for (int j = 0; j < 8; ++j) {
            bf16x8 vf = *(const bf16x8*)(lVt + (j * 16 + l15) * 40 + lg * 8);
            o[j] = __builtin_amdgcn_mfma_f32_16x16x32_bf16(pf, vf, o[j], 0, 0, 0);
        }
        __syncthreads();
    }

    for (int d = 1; d < 16; d <<= 1)
        for (int r = 0; r < 4; ++r) lrow[r] += __shfl_xor(lrow[r], d);
    float inv[4];
    for (int r = 0; r < 4; ++r) inv[r] = 1.f / lrow[r];
    bf16* Ob = O + ((size_t)b * 2048 + qw) * 2048 + h * 128;
    for (int j = 0; j < 8; ++j)
        for (int r = 0; r < 4; ++r)
            Ob[(size_t)(lg * 4 + r) * 2048 + j * 16 + l15] = (bf16)(o[j][r] * inv[r]);
}

extern "C" void kernel_launch(void* const* d_in, const int* in_sizes, int n_in,
                              void* d_out, int out_size, void* d_ws, size_t ws_size,
                              hipStream_t stream) {
    const float* x     = (const float*)d_in[0];   // [8192][2048] f32
    const float* wqkv  = (const float*)d_in[1];   // [2048][6144] f32
    const float* wproj = (const float*)d_in[2];   // [2048][2048] f32
    float* out = (float*)d_out;                   // [8192][2048] f32

    char* ws = (char*)d_ws;
    bf16* xb     = (bf16*)(ws);                                   // 33554432 B
    bf16* wqkvT  = (bf16*)(ws + 33554432);                        // 25165824 B
    bf16* wprojT = (bf16*)(ws + 33554432 + 25165824);             //  8388608 B
    bf16* QKV    = (bf16*)(ws + 33554432 + 25165824 + 8388608);   // 100663296 B
    bf16* Obuf   = xb;  // aliases xb — x dead after GEMM1

    cast_f32_bf16<<<dim3(16384), 256, 0, stream>>>(x, xb, (long)8192 * 2048);
    transpose_cast<<<dim3(192, 64), 256, 0, stream>>>(wqkv, wqkvT, 2048, 6144);
    transpose_cast<<<dim3(64, 64), 256, 0, stream>>>(wproj, wprojT, 2048, 2048);
    gemm_bt<bf16><<<dim3(48, 64), 256, 0, stream>>>(xb, wqkvT, QKV, 8192, 6144, 2048);
    attn_fwd<<<dim3(32, 64), 256, 0, stream>>>(QKV, Obuf);
    gemm_bt<float><<<dim3(16, 64), 256, 0, stream>>>(Obuf, wprojT, out, 8192, 2048, 2048);
}

// Round 4
// 657.010 us; speedup vs baseline: 1.4027x; 1.1559x over previous
//
#include <hip/hip_runtime.h>
#include <hip/hip_bf16.h>
#include <math.h>

typedef __bf16 bf16;
typedef __bf16 bf16x8 __attribute__((ext_vector_type(8)));
typedef float f32x4 __attribute__((ext_vector_type(4)));

#define AS1(p) ((const __attribute__((address_space(1))) void*)(p))
#define AS3(p) ((__attribute__((address_space(3))) void*)(p))

__device__ __forceinline__ void gl_lds16(const bf16* g, bf16* l) {
    __builtin_amdgcn_global_load_lds(AS1(g), AS3(l), 16, 0, 0);
}

// ---------------- cast f32 -> bf16, vectorized ----------------
__global__ __launch_bounds__(256) void cast_f32_bf16(const float* __restrict__ in,
                                                     bf16* __restrict__ out, long n) {
    long i = ((long)blockIdx.x * 256 + threadIdx.x) * 4;
    if (i + 3 < n) {
        float4 v = *(const float4*)(in + i);
        out[i + 0] = (bf16)v.x;
        out[i + 1] = (bf16)v.y;
        out[i + 2] = (bf16)v.z;
        out[i + 3] = (bf16)v.w;
    }
}

// ---------------- transpose + cast: in[R][C] f32 -> out[C][R] bf16 ----------------
__global__ __launch_bounds__(256) void transpose_cast(const float* __restrict__ in,
                                                      bf16* __restrict__ out,
                                                      int R, int Cc) {
    __shared__ float tile[32][33];
    const int t = threadIdx.x;
    const int r0 = blockIdx.y * 32, c0 = blockIdx.x * 32;
    for (int i = 0; i < 4; ++i) {
        int idx = t + i * 256;
        int r = idx >> 5, c = idx & 31;
        tile[r][c] = in[(size_t)(r0 + r) * Cc + c0 + c];
    }
    __syncthreads();
    for (int i = 0; i < 4; ++i) {
        int idx = t + i * 256;
        int r = idx >> 5, c = idx & 31;
        out[(size_t)(c0 + r) * R + r0 + c] = (bf16)tile[c][r];
    }
}

// ---------------- GEMM: C[M][N] = A[M][K] * B, with BT[N][K] given (bf16 in) ---------
template <typename OT>
__global__ __launch_bounds__(256) void gemm_bt(const bf16* __restrict__ A,
                                               const bf16* __restrict__ BT,
                                               OT* __restrict__ C,
                                               int M, int N, int K) {
    __shared__ bf16 lA[128 * 32];
    __shared__ bf16 lB[128 * 32];
    const int t = threadIdx.x;
    const int lane = t & 63;
    const int w = t >> 6;
    const int wr = w >> 1, wc = w & 1;
    const int l15 = lane & 15, lg = lane >> 4;
    const int bm = blockIdx.y, bn = blockIdx.x;

    const bf16* Abase = A + (size_t)bm * 128 * K;
    const bf16* Bbase = BT + (size_t)bn * 128 * K;

    f32x4 acc[4][4] = {};

    for (int k0 = 0; k0 < K; k0 += 32) {
        for (int j = 0; j < 2; ++j) {
            int c = j * 256 + t;                 // chunk id 0..511
            int r = c >> 2, col = (c & 3) * 8;   // tile row, elem col
            gl_lds16(Abase + (size_t)r * K + k0 + col, lA + (size_t)(j * 256 + w * 64) * 8);
            gl_lds16(Bbase + (size_t)r * K + k0 + col, lB + (size_t)(j * 256 + w * 64) * 8);
        }
        __syncthreads();
        bf16x8 af[4], bfr[4];
        for (int m = 0; m < 4; ++m)
            af[m] = *(const bf16x8*)(lA + (wr * 64 + m * 16 + l15) * 32 + lg * 8);
        for (int n = 0; n < 4; ++n)
            bfr[n] = *(const bf16x8*)(lB + (wc * 64 + n * 16 + l15) * 32 + lg * 8);
        for (int m = 0; m < 4; ++m)
            for (int n = 0; n < 4; ++n)
                acc[m][n] = __builtin_amdgcn_mfma_f32_16x16x32_bf16(af[m], bfr[n], acc[m][n], 0, 0, 0);
        __syncthreads();
    }

    for (int m = 0; m < 4; ++m)
        for (int n = 0; n < 4; ++n) {
            int row = bm * 128 + wr * 64 + m * 16 + lg * 4;
            int col = bn * 128 + wc * 64 + n * 16 + l15;
            for (int r = 0; r < 4; ++r)
                C[(size_t)(row + r) * N + col] = (OT)acc[m][n][r];
        }
}

// ---------------- causal flash attention ----------------
// QKV[8192][6144] bf16. grid: (T/64, B*H), 4 waves, each wave 16 q-rows.
// KVBLK=64. lK and lVt XOR-chunk-swizzled; lP stride 68. Staging pipelined under PV.
__global__ __launch_bounds__(256, 3) void attn_fwd(const bf16* __restrict__ QKV,
                                                   bf16* __restrict__ O) {
    __shared__ bf16 lK[64 * 128];    // [64 kv][16 chunks of 8], chunk ^ (row&7)
    __shared__ bf16 lVt[128 * 64];   // V^T [128 hd][8 chunks of 8], chunk ^ (row&7)
    __shared__ bf16 lP[4][16 * 68];  // per-wave P [16 q][64 kv], row stride 68

    const int t = threadIdx.x, lane = t & 63, w = t >> 6;
    const int l15 = lane & 15, lg = lane >> 4;
    const int bh = blockIdx.y;
    const int b = bh >> 4, h = bh & 15;
    const int q0 = ((int)gridDim.x - 1 - (int)blockIdx.x) * 64;  // largest work first
    const int qw = q0 + w * 16;
    const size_t rs = 6144;

    const bf16* Qb = QKV + (size_t)b * 2048 * rs + h * 128;
    const bf16* Kb = Qb + 2048;
    const bf16* Vb = Qb + 4096;

    bf16x8 qf[4];
    for (int kk = 0; kk < 4; ++kk)
        qf[kk] = *(const bf16x8*)(Qb + (size_t)(qw + l15) * rs + kk * 32 + lg * 8);

    f32x4 o[8] = {};
    float mrow[4] = {-1e30f, -1e30f, -1e30f, -1e30f};
    float lrow[4] = {0.f, 0.f, 0.f, 0.f};
    const float scale = 0.08838834764831845f;  // 128^-0.5

    const int kvp = t & 31;         // kv-pair id for V staging
    const int hd0 = (t >> 5) * 16;  // hd group base for V staging
    const int nt = q0 / 64 + 1;

    // prologue: stage K(0) via gl_lds, V(0) -> regs
    for (int j = 0; j < 4; ++j) {
        int c = j * 256 + t;
        int r = c >> 4, cc = c & 15;
        gl_lds16(Kb + (size_t)r * rs + ((cc ^ (r & 7)) << 3), lK + (size_t)c * 8);
    }
    bf16x8 vr0, vr1, vr2, vr3;
    {
        const bf16* p = Vb + (size_t)(2 * kvp) * rs + hd0;
        vr0 = *(const bf16x8*)(p);
        vr1 = *(const bf16x8*)(p + rs);
        vr2 = *(const bf16x8*)(p + 8);
        vr3 = *(const bf16x8*)(p + rs + 8);
    }

    for (int kt = 0; kt < nt; ++kt) {
        const int kv0 = kt * 64;
        __syncthreads();  // barrier A: drains vmcnt -> K(kt) in LDS, V(kt) in regs; lVt free

        // write V^T (swizzled chunks), packed u32
        for (int e = 0; e < 8; ++e) {
            union { bf16 h2[2]; unsigned u; } p0, p1;
            p0.h2[0] = vr0[e]; p0.h2[1] = vr1[e];
            p1.h2[0] = vr2[e]; p1.h2[1] = vr3[e];
            int r0 = hd0 + e, r1 = hd0 + 8 + e;
            *(unsigned*)(lVt + r0 * 64 + (((kvp >> 2) ^ (r0 & 7)) << 3) + ((kvp & 3) << 1)) = p0.u;
            *(unsigned*)(lVt + r1 * 64 + (((kvp >> 2) ^ (r1 & 7)) << 3) + ((kvp & 3) << 1)) = p1.u;
        }

        // S = Q K^T  (16 q x 64 kv)
        f32x4 s[4] = {};
        __builtin_amdgcn_s_setprio(1);
        for (int n = 0; n < 4; ++n) {
            int row = n * 16 + l15;
            for (int kk = 0; kk < 4; ++kk) {
                bf16x8 kf = *(const bf16x8*)(lK + row * 128 + (((kk * 4 + lg) ^ (row & 7)) << 3));
                s[n] = __builtin_amdgcn_mfma_f32_16x16x32_bf16(qf[kk], kf, s[n], 0, 0, 0);
            }
        }
        __builtin_amdgcn_s_setprio(0);

        // scale + causal mask
        float pv[4][4];
        for (int n = 0; n < 4; ++n)
            for (int r = 0; r < 4; ++r) {
                float x = s[n][r] * scale;
                int qg = qw + lg * 4 + r;
                int kg = kv0 + n * 16 + l15;
                pv[n][r] = (kg <= qg) ? x : -1e30f;
            }
        float tmax[4];
        for (int r = 0; r < 4; ++r)
            tmax[r] = fmaxf(fmaxf(pv[0][r], pv[1][r]), fmaxf(pv[2][r], pv[3][r]));
        for (int d = 1; d < 16; d <<= 1)
            for (int r = 0; r < 4; ++r)
                tmax[r] = fmaxf(tmax[r], __shfl_xor(tmax[r], d));
        float alpha[4];
        for (int r = 0; r < 4; ++r) {
            float mn = fmaxf(mrow[r], tmax[r]);
            alpha[r] = __expf(mrow[r] - mn);
            mrow[r] = mn;
        }
        for (int j = 0; j < 8; ++j)
            for (int r = 0; r < 4; ++r) o[j][r] *= alpha[r];
        for (int r = 0; r < 4; ++r) lrow[r] *= alpha[r];
        for (int n = 0; n < 4; ++n)
            for (int r = 0; r < 4; ++r) {
                float p = __expf(pv[n][r] - mrow[r]);
                lrow[r] += p;
                lP[w][(lg * 4 + r) * 68 + n * 16 + l15] = (bf16)p;
            }
        bf16x8 pf0 = *(const bf16x8*)(&lP[w][l15 * 68 + lg * 8]);
        bf16x8 pf1 = *(const bf16x8*)(&lP[w][l15 * 68 + 32 + lg * 8]);

        __syncthreads();  // barrier B: lVt fully written; lK reads done by all waves

        // prefetch next tile: K(t+1) -> lK (gl_lds), V(t+1) -> regs; fly during PV
        if (kt + 1 < nt) {
            const int nk = kv0 + 64;
            for (int j = 0; j < 4; ++j) {
                int c = j * 256 + t;
                int r = c >> 4, cc = c & 15;
                gl_lds16(Kb + (size_t)(nk + r) * rs + ((cc ^ (r & 7)) << 3), lK + (size_t)c * 8);
            }
            const bf16* p = Vb + (size_t)(nk + 2 * kvp) * rs + hd0;
            vr0 = *(const bf16x8*)(p);
            vr1 = *(const bf16x8*)(p + rs);
            vr2 = *(const bf16x8*)(p + 8);
            vr3 = *(const bf16x8*)(p + rs + 8);
        }

        // O += P V
        __builtin_amdgcn_s_setprio(1);
        for (int j = 0; j < 8; ++j) {
            int R = j * 16 + l15;
            bf16x8 vfa = *(const bf16x8*)(lVt + R * 64 + ((lg ^ (R & 7)) << 3));
            bf16x8 vfb = *(const bf16x8*)(lVt + R * 64 + (((4 + lg) ^ (R & 7)) << 3));
            o[j] = __builtin_amdgcn_mfma_f32_16x16x32_bf16(pf0, vfa, o[j], 0, 0, 0);
            o[j] = __builtin_amdgcn_mfma_f32_16x16x32_bf16(pf1, vfb, o[j], 0, 0, 0);
        }
        __builtin_amdgcn_s_setprio(0);
    }

    // final row-sum reduce + normalize + write O[b*2048+q][h*128+d]
    for (int d = 1; d < 16; d <<= 1)
        for (int r = 0; r < 4; ++r) lrow[r] += __shfl_xor(lrow[r], d);
    float inv[4];
    for (int r = 0; r < 4; ++r) inv[r] = 1.f / lrow[r];
    bf16* Ob = O + ((size_t)b * 2048 + qw) * 2048 + h * 128;
    for (int j = 0; j < 8; ++j)
        for (int r = 0; r < 4; ++r)
            Ob[(size_t)(lg * 4 + r) * 2048 + j * 16 + l15] = (bf16)(o[j][r] * inv[r]);
}

extern "C" void kernel_launch(void* const* d_in, const int* in_sizes, int n_in,
                              void* d_out, int out_size, void* d_ws, size_t ws_size,
                              hipStream_t stream) {
    const float* x     = (const float*)d_in[0];   // [8192][2048] f32
    const float* wqkv  = (const float*)d_in[1];   // [2048][6144] f32
    const float* wproj = (const float*)d_in[2];   // [2048][2048] f32
    float* out = (float*)d_out;                   // [8192][2048] f32

    char* ws = (char*)d_ws;
    bf16* xb     = (bf16*)(ws);                                   // 33554432 B
    bf16* wqkvT  = (bf16*)(ws + 33554432);                        // 25165824 B
    bf16* wprojT = (bf16*)(ws + 33554432 + 25165824);             //  8388608 B
    bf16* QKV    = (bf16*)(ws + 33554432 + 25165824 + 8388608);   // 100663296 B
    bf16* Obuf   = xb;  // aliases xb — x dead after GEMM1

    cast_f32_bf16<<<dim3(16384), 256, 0, stream>>>(x, xb, (long)8192 * 2048);
    transpose_cast<<<dim3(192, 64), 256, 0, stream>>>(wqkv, wqkvT, 2048, 6144);
    transpose_cast<<<dim3(64, 64), 256, 0, stream>>>(wproj, wprojT, 2048, 2048);
    gemm_bt<bf16><<<dim3(48, 64), 256, 0, stream>>>(xb, wqkvT, QKV, 8192, 6144, 2048);
    attn_fwd<<<dim3(32, 64), 256, 0, stream>>>(QKV, Obuf);
    gemm_bt<float><<<dim3(16, 64), 256, 0, stream>>>(Obuf, wprojT, out, 8192, 2048, 2048);
}